// Round 4
// baseline (787.229 us; speedup 1.0000x reference)
//
#include <hip/hip_runtime.h>
#include <cmath>

#define NB 4
#define NC 128
#define NH 128
#define NW 128
#define HD 64
#define WD 64
#define NL 4096      // 64*64 positions / patches
#define NPIX 16384   // 128*128 output pixels per batch
#define KDIM 1152    // 128*3*3
#define SM_SCALE 2550.0f
#define CUT 40.0f
#define CUTS 0.216f  // candidate margin in score units
#define MAXENT 8
#define MAXC 256
#define PLMAX 32     // 4 positions x MAXENT survivors
#define GPT 64       // pixels per gather block

struct Ent { int l; float p; };

typedef __attribute__((ext_vector_type(4))) float f32x4;
typedef __attribute__((ext_vector_type(8))) short s16x8;

__device__ __forceinline__ unsigned short f2bf(float x) {
  unsigned u = __float_as_uint(x);
  return (unsigned short)((u + 0x7fffu + ((u >> 16) & 1u)) >> 16);
}
__device__ __forceinline__ float bf2f(unsigned short h) {
  return __uint_as_float(((unsigned)h) << 16);
}
__device__ __forceinline__ unsigned fenc(float v) {   // order-preserving float->uint
  unsigned b = __float_as_uint(v);
  return (b >> 31) ? ~b : (b | 0x80000000u);
}
__device__ __forceinline__ float fdec(unsigned e) {
  unsigned b = (e >> 31) ? (e ^ 0x80000000u) : ~e;    // e==0 -> NaN (no candidates)
  return __uint_as_float(b);
}
__device__ __forceinline__ void gload_lds16(const void* g, void* l) {
  __builtin_amdgcn_global_load_lds(
      (const __attribute__((address_space(1))) void*)g,
      (__attribute__((address_space(3))) void*)l, 16, 0, 0);
}

// ---------- prep ----------
__global__ void k_prep(const float* __restrict__ f, const float* __restrict__ b,
                       float* __restrict__ fd, float* __restrict__ bd) {
  int i = blockIdx.x * blockDim.x + threadIdx.x;
  if (i >= NB*NC*HD*WD) return;
  int x = i & 63, y = (i >> 6) & 63, c = (i >> 12) & 127, bb = i >> 19;
  int src = ((bb*NC + c)*NH + 2*y)*NW + 2*x;
  fd[i] = f[src];
  bd[i] = b[src];
}

__global__ void k_sq(const float* __restrict__ bd, double* __restrict__ sq) {
  int i = blockIdx.x * blockDim.x + threadIdx.x;
  if (i >= NB*HD*WD) return;
  int x = i & 63, y = (i >> 6) & 63, bb = i >> 12;
  double s = 0.0;
  const float* p = bd + (size_t)bb*NC*HD*WD + y*WD + x;
  for (int c = 0; c < NC; ++c) {
    double v = (double)p[(size_t)c*HD*WD];
    s += v*v;
  }
  sq[i] = s;
}

__global__ void k_normmm(const double* __restrict__ sq, const float* __restrict__ mask,
                         float* __restrict__ norm, float* __restrict__ mmv,
                         int* __restrict__ zb) {
  int i = blockIdx.x * blockDim.x + threadIdx.x;
  if (i >= NB*NL) return;
  int pw = i & 63, ph = (i >> 6) & 63, bb = i >> 12;
  double s = 0.0;
  for (int dh = -1; dh <= 1; ++dh) {
    int y = ph + dh; if ((unsigned)y >= 64u) continue;
    for (int dw = -1; dw <= 1; ++dw) {
      int x = pw + dw; if ((unsigned)x >= 64u) continue;
      s += sq[(bb*HD + y)*WD + x];
    }
  }
  norm[i] = (float)sqrt(s);
  float ms = 0.f;
  const float* mb = mask + (size_t)bb*512*512;
  for (int dh = -1; dh <= 1; ++dh) {
    int y = ph + dh; if ((unsigned)y >= 64u) continue;
    for (int dw = -1; dw <= 1; ++dw) {
      int x = pw + dw; if ((unsigned)x >= 64u) continue;
      ms += mb[(y*8)*512 + x*8];
    }
  }
  float m = (ms == 0.f) ? 1.f : 0.f;
  mmv[i] = m;
  if (m == 0.f) atomicAdd(&zb[bb], 1);
}

// ---------- transpose b to pixel-major b_t[bb][pix][c] ----------
__global__ __launch_bounds__(256) void k_btrans(const float* __restrict__ b,
                                                float* __restrict__ bt) {
  __shared__ float tile[32][33];
  int bb = blockIdx.z;
  int c0 = blockIdx.y * 32;
  int p0 = blockIdx.x * 32;
  int tx = threadIdx.x & 31, ty = threadIdx.x >> 5;   // 8 rows at a time
  const float* bp = b + (size_t)bb*NC*NPIX;
  #pragma unroll
  for (int r = 0; r < 32; r += 8)
    tile[r + ty][tx] = bp[(size_t)(c0 + r + ty)*NPIX + p0 + tx];
  __syncthreads();
  float* btp = bt + (size_t)bb*NPIX*NC;
  #pragma unroll
  for (int r = 0; r < 32; r += 8)
    btp[(size_t)(p0 + r + ty)*NC + c0 + tx] = tile[tx][r + ty];
}

// ---------- im2col to bf16 ----------
__global__ __launch_bounds__(384) void k_im2col(const float* __restrict__ fd,
    const float* __restrict__ bd, unsigned short* __restrict__ Abf,
    unsigned short* __restrict__ Bbf, int bb) {
  int p = blockIdx.x;
  int t = threadIdx.x;
  int ihp = p >> 6, iwp = p & 63;
  const float* fdb = fd + (size_t)bb*NC*HD*WD;
  const float* bdb = bd + (size_t)bb*NC*HD*WD;
  for (int k = t; k < KDIM; k += 384) {
    int c = k / 9, r = k % 9;
    int y = ihp + r/3 - 1, x = iwp + (r % 3) - 1;
    bool inb = ((unsigned)y < 64u) && ((unsigned)x < 64u);
    float av = inb ? fdb[(c*HD + y)*WD + x] : 0.f;
    float bv = inb ? bdb[(c*HD + y)*WD + x] : 0.f;
    Abf[(size_t)p*KDIM + k] = f2bf(av);
    Bbf[(size_t)p*KDIM + k] = f2bf(bv);
  }
}

// ---------- bf16 MFMA screening GEMM + fused per-row max ----------
__global__ __launch_bounds__(256) void k_gemm_bf16(
    const unsigned short* __restrict__ A, const unsigned short* __restrict__ B,
    const float* __restrict__ nrm, const float* __restrict__ mm,
    unsigned short* __restrict__ Sb, unsigned* __restrict__ rowmax) {
  __shared__ __align__(16) unsigned short As[128*32];
  __shared__ __align__(16) unsigned short Bs[128*32];
  __shared__ unsigned rmx_s[128];
  int t = threadIdx.x;
  int w = t >> 6, l = t & 63;
  int by = blockIdx.y, bx = blockIdx.x;
  int wr = w >> 1, wc = w & 1;
  f32x4 acc[4][4] = {};
  int aoff[4], boff[4];
  #pragma unroll
  for (int m = 0; m < 4; ++m) {
    aoff[m] = ((wr*64 + m*16 + (l & 15)) * 32 + ((l >> 4) * 8)) * 2;
    boff[m] = ((wc*64 + m*16 + (l & 15)) * 32 + ((l >> 4) * 8)) * 2;
  }
  const char* Ab = (const char*)A;
  const char* Bb = (const char*)B;
  char* AsB = (char*)As;
  char* BsB = (char*)Bs;
  int off = (w*2) * 1024 + l * 16;
  int r0 = off >> 6, cb0 = off & 63;
  int off1 = off + 1024;
  int r1 = off1 >> 6, cb1 = off1 & 63;
  for (int k0 = 0; k0 < KDIM; k0 += 32) {
    gload_lds16(Ab + ((size_t)(by*128 + r0) * KDIM + k0) * 2 + cb0, AsB + (w*2+0)*1024);
    gload_lds16(Ab + ((size_t)(by*128 + r1) * KDIM + k0) * 2 + cb1, AsB + (w*2+1)*1024);
    gload_lds16(Bb + ((size_t)(bx*128 + r0) * KDIM + k0) * 2 + cb0, BsB + (w*2+0)*1024);
    gload_lds16(Bb + ((size_t)(bx*128 + r1) * KDIM + k0) * 2 + cb1, BsB + (w*2+1)*1024);
    __syncthreads();
    s16x8 af[4], bf[4];
    #pragma unroll
    for (int m = 0; m < 4; ++m) af[m] = *(const s16x8*)(AsB + aoff[m]);
    #pragma unroll
    for (int n = 0; n < 4; ++n) bf[n] = *(const s16x8*)(BsB + boff[n]);
    #pragma unroll
    for (int m = 0; m < 4; ++m)
      #pragma unroll
      for (int n = 0; n < 4; ++n)
        acc[m][n] = __builtin_amdgcn_mfma_f32_16x16x32_bf16(af[m], bf[n], acc[m][n], 0, 0, 0);
    __syncthreads();
  }
  if (t < 128) rmx_s[t] = 0u;
  __syncthreads();
  int cr = l >> 4;     // 0..3
  int cc = l & 15;
  #pragma unroll
  for (int n = 0; n < 4; ++n) {
    int col = bx*128 + wc*64 + n*16 + cc;
    float rn = 1.f / fmaxf(nrm[col], 1e-4f);
    bool um = (mm[col] != 0.f);
    #pragma unroll
    for (int m = 0; m < 4; ++m) {
      int lrow = wr*64 + m*16 + cr*4;
      int grow = by*128 + lrow;
      #pragma unroll
      for (int j = 0; j < 4; ++j) {
        unsigned short sbv = f2bf(acc[m][n][j] * rn);
        Sb[(size_t)(grow + j) * NL + col] = sbv;
        if (um) atomicMax(&rmx_s[lrow + j], fenc(bf2f(sbv)));
      }
    }
  }
  __syncthreads();
  if (t < 128) atomicMax(&rowmax[by*128 + t], rmx_s[t]);
}

// ---------- fused scan + exact rescore ----------
__global__ __launch_bounds__(256) void k_rescore2(const unsigned short* __restrict__ Sb,
    const float* __restrict__ mmv, const unsigned* __restrict__ rowmax,
    const float* __restrict__ fd, const float* __restrict__ bd,
    const float* __restrict__ nrm, const int* __restrict__ zb,
    int* __restrict__ cnt, Ent* __restrict__ ent, float* __restrict__ ooff, int bb) {
  int p = blockIdx.x, t = threadIdx.x;
  int wid = t >> 6, lane = t & 63;
  int ihp = p >> 6, iwp = p & 63;
  __shared__ float fpat[KDIM];
  __shared__ int cl[MAXC];
  __shared__ float cs[MAXC];
  __shared__ int cnt_s;
  if (t == 0) cnt_s = 0;
  const float* fdb = fd + (size_t)bb*NC*HD*WD;
  const float* bdb = bd + (size_t)bb*NC*HD*WD;
  for (int k = t; k < KDIM; k += 256) {
    int c = k / 9, r = k % 9;
    int y = ihp + r/3 - 1, x = iwp + (r % 3) - 1;
    fpat[k] = (((unsigned)y < 64u) && ((unsigned)x < 64u)) ? fdb[(c*HD + y)*WD + x] : 0.f;
  }
  __syncthreads();
  // scan this row of Sb for candidates
  float thr = fdec(rowmax[p]) - CUTS;   // NaN if no unmasked col
  const unsigned short* row = Sb + (size_t)p * NL;
  const float* mb = mmv + bb * NL;
  int l0 = t * 16;
  uint4 q0 = *(const uint4*)(row + l0);
  uint4 q1 = *(const uint4*)(row + l0 + 8);
  unsigned qq[8] = {q0.x,q0.y,q0.z,q0.w,q1.x,q1.y,q1.z,q1.w};
  #pragma unroll
  for (int h = 0; h < 8; ++h) {
    float v0 = bf2f((unsigned short)(qq[h] & 0xffffu));
    float v1 = bf2f((unsigned short)(qq[h] >> 16));
    int c0 = l0 + 2*h, c1 = l0 + 2*h + 1;
    if (mb[c0] != 0.f && v0 >= thr) {
      int slot = atomicAdd(&cnt_s, 1);
      if (slot < MAXC) cl[slot] = c0;
    }
    if (mb[c1] != 0.f && v1 >= thr) {
      int slot = atomicAdd(&cnt_s, 1);
      if (slot < MAXC) cl[slot] = c1;
    }
  }
  __syncthreads();
  int nc = cnt_s < MAXC ? cnt_s : MAXC;
  if (t == 0 && nc > 1) {        // deterministic order: sort candidates by l
    for (int a = 1; a < nc; ++a) {
      int v = cl[a]; int q = a - 1;
      while (q >= 0 && cl[q] > v) { cl[q+1] = cl[q]; --q; }
      cl[q+1] = v;
    }
  }
  __syncthreads();
  for (int a = wid; a < nc; a += 4) {
    int lidx = cl[a]; int ph = lidx >> 6, pw = lidx & 63;
    float sum = 0.f;
    #pragma unroll
    for (int kk = 0; kk < 18; ++kk) {     // 1152 = 18*64
      int k = kk*64 + lane;
      int c = k / 9, r = k % 9;
      int y = ph + r/3 - 1, x = pw + (r % 3) - 1;
      float bv = (((unsigned)y < 64u) && ((unsigned)x < 64u)) ? bdb[(c*HD + y)*WD + x] : 0.f;
      sum = fmaf(fpat[k], bv, sum);
    }
    #pragma unroll
    for (int o = 32; o > 0; o >>= 1) sum += __shfl_xor(sum, o, 64);
    if (lane == 0) cs[a] = sum / fmaxf(nrm[bb*NL + lidx], 1e-4f);
  }
  __syncthreads();
  if (t == 0) {
    float smax = -3e38f; int sidx = 0x7fffffff;
    for (int a = 0; a < nc; ++a)
      if (cs[a] > smax) { smax = cs[a]; sidx = cl[a]; }   // sorted by l
    int Z = zb[bb];
    size_t base = (size_t)(bb*NL + p) * MAXENT;
    if (nc == 0) {
      cnt[bb*NL + p] = 0;
      ooff[((bb*2 + 0)*HD + ihp)*WD + iwp] = (float)(0 - ihp);
      ooff[((bb*2 + 1)*HD + ihp)*WD + iwp] = (float)(0 - iwp);
    } else {
      float xm = smax * SM_SCALE;
      if (Z > 0) xm = fmaxf(xm, 0.f);
      float den = 0.f;
      for (int a = 0; a < nc; ++a) {
        float d = cs[a] * SM_SCALE - xm;
        if (d > -CUT) den += expf(d);
      }
      if (Z > 0 && -xm > -CUT) den += (float)Z * expf(-xm);
      int n = 0;
      for (int a = 0; a < nc && n < MAXENT; ++a) {
        float d = cs[a] * SM_SCALE - xm;
        if (d > -CUT) { ent[base + n].l = cl[a]; ent[base + n].p = expf(d) / den; ++n; }
      }
      cnt[bb*NL + p] = n;
      ooff[((bb*2 + 0)*HD + ihp)*WD + iwp] = (float)((sidx >> 6) - ihp);
      ooff[((bb*2 + 1)*HD + ihp)*WD + iwp] = (float)((sidx & 63) - iwp);
    }
  }
}

// ---------- plan: per output pixel, channel-independent contribution list ----------
__global__ void k_plan(const int* __restrict__ cnt, const Ent* __restrict__ ent,
                       int* __restrict__ npl, int* __restrict__ offs,
                       float* __restrict__ wts) {
  int i = blockIdx.x * blockDim.x + threadIdx.x;
  if (i >= NB*NPIX) return;
  int pix = i & (NPIX-1); int bb = i >> 14;
  int oh = pix >> 7, ow = pix & 127;
  int ihlo = (oh - 1) >> 1;
  int iwlo = (ow - 1) >> 1;
  int n = 0;
  #pragma unroll
  for (int a = 0; a < 2; ++a) {
    int ih = ihlo + a;
    if ((unsigned)ih >= 64u) continue;
    #pragma unroll
    for (int d = 0; d < 2; ++d) {
      int iw = iwlo + d;
      if ((unsigned)iw >= 64u) continue;
      int pidx = bb*NL + ih*WD + iw;
      int nn = cnt[pidx];
      const Ent* ep = ent + (size_t)pidx*MAXENT;
      for (int j = 0; j < nn; ++j) {
        Ent e = ep[j];
        int ph = e.l >> 6, pw = e.l & 63;
        int yy = oh + 2*(ph - ih);
        int xx = ow + 2*(pw - iw);
        if ((unsigned)yy < 128u && (unsigned)xx < 128u) {
          offs[((size_t)bb*PLMAX + n)*NPIX + pix] = yy*NW + xx;
          wts[((size_t)bb*PLMAX + n)*NPIX + pix] = e.p;
          ++n;
        }
      }
    }
  }
  npl[i] = n;
}

// ---------- gather v3: pixel-major b_t, all channels per block ----------
__global__ __launch_bounds__(256) void k_gather3(const float* __restrict__ bt,
    const int* __restrict__ npl, const int* __restrict__ offs,
    const float* __restrict__ wts, float* __restrict__ yout) {
  __shared__ float acc_s[GPT][NC + 1];
  int bb = blockIdx.z;
  int pixbase = blockIdx.x * GPT;
  int t = threadIdx.x;
  int c = t & 127;
  int half = t >> 7;
  const float* btb = bt + (size_t)bb*NPIX*NC;
  for (int i = 0; i < GPT/2; ++i) {
    int pixloc = half*(GPT/2) + i;
    int pix = pixbase + pixloc;
    int n = npl[bb*NPIX + pix];
    float acc = 0.f;
    for (int j = 0; j < n; ++j) {
      int off = offs[((size_t)bb*PLMAX + j)*NPIX + pix];
      float wv = wts[((size_t)bb*PLMAX + j)*NPIX + pix];
      acc = fmaf(wv, btb[(size_t)off*NC + c], acc);
    }
    acc_s[pixloc][c] = acc * 0.25f;
  }
  __syncthreads();
  int oc = t >> 1, i0 = (t & 1) * (GPT/2);
  float* yp = yout + ((size_t)bb*NC + oc)*NPIX + pixbase + i0;
  #pragma unroll
  for (int i = 0; i < GPT/2; i += 4) {
    float4 v = make_float4(acc_s[i0+i][oc], acc_s[i0+i+1][oc],
                           acc_s[i0+i+2][oc], acc_s[i0+i+3][oc]);
    *(float4*)(yp + i) = v;
  }
}

extern "C" void kernel_launch(void* const* d_in, const int* in_sizes, int n_in,
                              void* d_out, int out_size, void* d_ws, size_t ws_size,
                              hipStream_t stream) {
  const float* f = (const float*)d_in[0];
  const float* b = (const float*)d_in[1];
  const float* mask = (const float*)d_in[2];
  float* out = (float*)d_out;

  char* w = (char*)d_ws;
  float* fd   = (float*)w;  w += (size_t)NB*NC*HD*WD*4;
  float* bd   = (float*)w;  w += (size_t)NB*NC*HD*WD*4;
  double* sq  = (double*)w; w += (size_t)NB*HD*WD*8;
  float* norm = (float*)w;  w += (size_t)NB*NL*4;
  float* mmv  = (float*)w;  w += (size_t)NB*NL*4;
  int* cnt    = (int*)w;    w += (size_t)NB*NL*4;
  Ent* ent    = (Ent*)w;    w += (size_t)NB*NL*MAXENT*sizeof(Ent);
  unsigned short* Abf = (unsigned short*)w; w += (size_t)NL*KDIM*2;
  unsigned short* Bbf = (unsigned short*)w; w += (size_t)NL*KDIM*2;
  int* zb     = (int*)w;    w += 64;
  unsigned* rowmax = (unsigned*)w; w += (size_t)NL*4;
  int* npl    = (int*)w;    w += (size_t)NB*NPIX*4;
  int* offs   = (int*)w;    w += (size_t)NB*PLMAX*NPIX*4;
  float* wts  = (float*)w;  w += (size_t)NB*PLMAX*NPIX*4;
  float* bt   = (float*)w;  w += (size_t)NB*NPIX*NC*4;
  unsigned short* Sb = (unsigned short*)w;  // 32 MB, reused per batch

  int n1 = NB*NC*HD*WD;
  k_prep<<<(n1+255)/256, 256, 0, stream>>>(f, b, fd, bd);
  k_sq<<<(NB*HD*WD+255)/256, 256, 0, stream>>>(bd, sq);
  hipMemsetAsync(zb, 0, 64, stream);
  k_normmm<<<(NB*NL+255)/256, 256, 0, stream>>>(sq, mask, norm, mmv, zb);
  k_btrans<<<dim3(NPIX/32, NC/32, NB), 256, 0, stream>>>(b, bt);

  float* ooff = out + (size_t)NB*NC*NH*NW;
  for (int bb = 0; bb < NB; ++bb) {
    hipMemsetAsync(rowmax, 0, (size_t)NL*4, stream);
    k_im2col<<<NL, 384, 0, stream>>>(fd, bd, Abf, Bbf, bb);
    k_gemm_bf16<<<dim3(32, 32), 256, 0, stream>>>(Abf, Bbf, norm + bb*NL, mmv + bb*NL, Sb, rowmax);
    k_rescore2<<<NL, 256, 0, stream>>>(Sb, mmv, rowmax, fd, bd, norm, zb, cnt, ent, ooff, bb);
  }
  k_plan<<<(NB*NPIX+255)/256, 256, 0, stream>>>(cnt, ent, npl, offs, wts);
  k_gather3<<<dim3(NPIX/GPT, 1, NB), 256, 0, stream>>>(bt, npl, offs, wts, out);
}